// Round 1
// 509.541 us; speedup vs baseline: 1.2235x; 1.2235x over previous
//
#include <hip/hip_runtime.h>

// ---------------- problem dims ----------------
#define T_DIM 256
#define B_DIM 512
#define D_DIM 128
#define H_DIM 128
#define A_DIM 8
#define N_ROWS (T_DIM*B_DIM)   // 131072 flattened rows
#define NT (N_ROWS/16)         // 8192 row tiles of 16
#define NWIN 8                 // time windows of 32 for the GRU
#define LOG2E 1.4426950408889634f

typedef __attribute__((ext_vector_type(4))) float f32x4;
typedef __attribute__((ext_vector_type(8))) short bf16x8;     // 8 bf16 in 4 VGPRs
typedef __attribute__((ext_vector_type(4))) short bf16x4;
typedef __attribute__((ext_vector_type(8))) _Float16 f16x8;   // 8 f16 in 4 VGPRs
typedef __attribute__((ext_vector_type(4))) unsigned u32x4;

// ---------------- workspace layout (bytes) ----------------
#define OFF_PSUM   0ull
#define OFF_PSQ    1048576ull
#define OFF_STATM  2097152ull
#define OFF_STATI  2097664ull
#define OFF_WEMB   2098176ull              // 16384 el bf16
#define OFF_WI     2130944ull              // 49152 el bf16
#define OFF_WH     2229248ull              // 49152 el f16 (pre-scaled by log2e / 2log2e)
#define OFF_WACT   2425856ull              // 16384 el bf16
#define OFF_WHEAD  2458624ull              // 2048 el bf16
#define OFF_TLO    2462720ull              // 8*32 int
#define OFF_UH     2463744ull              // 8*512 bytes
#define OFF_XG     4194304ull              // 96 MB (C/D-frag order; r/z pre-biased+scaled)
#define OFF_YS     104857600ull            // 32 MB (C/D-frag order)

// ---------------- output layout (f32 elements) ----------------
#define OUT_H      0
#define OUT_ALPHA  65536
#define OUT_BETA   1114112
#define OUT_M      2162688
#define OUT_S      2162816

__device__ inline short f2bf(float x){              // RNE f32->bf16
  union { float f; unsigned u; } v; v.f = x;
  unsigned r = v.u + 0x7FFFu + ((v.u>>16)&1u);
  return (short)(r>>16);
}
__device__ inline float bf2f(short h){
  union { unsigned u; float f; } v; v.u = ((unsigned)(unsigned short)h)<<16; return v.f;
}

// LDS swizzle: halfword index within a row of stride 136, XOR'd by row.
// Kills the ~8-way bank conflict of stride-136 b128 column reads while
// preserving 16B alignment (XOR operand is a multiple of 8 halfwords).
__device__ inline int swz(int row, int col){ return row*136 + (col ^ ((row&7)<<3)); }

// ============ K1: per-column partial sum / sumsq over obs rows ============
__global__ __launch_bounds__(256) void k_partial(const float* __restrict__ obs,
                                                 double* __restrict__ psum,
                                                 double* __restrict__ psq){
  int tid = threadIdx.x; int col = tid & 127; int rh = tid >> 7;
  double s = 0.0, q = 0.0;
  for (int r = blockIdx.x*2 + rh; r < N_ROWS; r += 2048){
    float v = obs[(size_t)r*D_DIM + col];
    s += (double)v; q += (double)v*(double)v;
  }
  __shared__ double ls[256], lq[256];
  ls[tid]=s; lq[tid]=q; __syncthreads();
  if (rh==0){
    psum[(size_t)blockIdx.x*128 + col] = ls[tid] + ls[tid+128];
    psq [(size_t)blockIdx.x*128 + col] = lq[tid] + lq[tid+128];
  }
}

// ============ K2: finalize Welford (chunk-combine) ============
__global__ __launch_bounds__(1024) void k_stats(const double* __restrict__ psum,
                                                const double* __restrict__ psq,
                                                const float* __restrict__ mean_obs,
                                                const float* __restrict__ welfS,
                                                const int* __restrict__ runcnt,
                                                float* __restrict__ outM, float* __restrict__ outS,
                                                float* __restrict__ wsM,  float* __restrict__ wsI){
  int tid = threadIdx.x; int col = tid & 127; int seg = tid >> 7;
  double s=0.0, q=0.0;
  for (int b=seg; b<1024; b+=8){ s += psum[(size_t)b*128+col]; q += psq[(size_t)b*128+col]; }
  __shared__ double ls[1024], lq[1024];
  ls[tid]=s; lq[tid]=q; __syncthreads();
  if (seg==0){
    for (int b=1;b<8;b++){ s += ls[b*128+col]; q += lq[b*128+col]; }
    double c0 = (double)runcnt[0];
    double Nn = (double)N_ROWS;
    double n  = c0 + Nn;
    double M0 = (double)mean_obs[col], S0 = (double)welfS[col];
    double mb = s / Nn;
    double delta = mb - M0;
    double M = M0 + delta * Nn / n;
    double M2b = q - Nn*mb*mb;
    double S = S0 + M2b + delta*delta*c0*Nn/n;
    double var = S / (n - 1.0);
    float inv = (float)(1.0/(sqrt(var)+1e-8));
    outM[col] = (float)M; outS[col] = (float)S;
    wsM[col]  = (float)M; wsI[col]  = inv;
  }
}

// ============ K3: all weight packs in ONE launch ============
// frag layout: ((ct*4+kb)*64+lane)*8+j holds W[k=kb*32+(lane>>4)*8+j][n=ct*16+(lane&15)]
// Wh (fmt=1) is pre-scaled: r/z columns x log2e, n columns x 2*log2e, so the
// GRU gate transcendentals become a single v_exp_f32 (exp2) each.
__global__ void k_pack_all(const float* __restrict__ W_emb, const float* __restrict__ Wi,
                           const float* __restrict__ Wh,    const float* __restrict__ W_act,
                           const float* __restrict__ W_al,  const float* __restrict__ W_be,
                           short* __restrict__ Bemb, short* __restrict__ BWi,
                           short* __restrict__ BWh,  short* __restrict__ Bact,
                           short* __restrict__ Bhead){
  int gidx = blockIdx.x*256 + threadIdx.x;
  if (gidx >= 133120) return;
  if (gidx >= 131072){
    int idx = gidx - 131072;
    int j = idx & 7, lane = (idx>>3)&63, kb = (idx>>9)&3;
    int k = kb*32 + (lane>>4)*8 + j;
    int n = lane & 15;
    float wv = (n<8) ? W_al[(size_t)k*8 + n] : W_be[(size_t)k*8 + (n-8)];
    Bhead[idx] = f2bf(wv);
    return;
  }
  const float* src; short* dst; int C; int fmt; int idx;   // fmt 0=bf16 1=f16
  if (gidx < 16384)      { src=W_emb; dst=Bemb; C=128; fmt=0; idx=gidx; }
  else if (gidx < 65536) { src=Wi;    dst=BWi;  C=384; fmt=0; idx=gidx-16384; }
  else if (gidx < 114688){ src=Wh;    dst=BWh;  C=384; fmt=1; idx=gidx-65536; }
  else                   { src=W_act; dst=Bact; C=128; fmt=0; idx=gidx-114688; }
  int j = idx & 7, lane = (idx>>3)&63, kb = (idx>>9)&3, ct = idx>>11;
  int k = kb*32 + (lane>>4)*8 + j;
  int n = ct*16 + (lane&15);
  float wv = src[(size_t)k*C + n];
  short h;
  if (fmt==0) h = f2bf(wv);
  else {
    wv *= (n < 256) ? LOG2E : (2.f*LOG2E);
    union { _Float16 hf; short s; } u; u.hf = (_Float16)wv; h = u.s;
  }
  dst[idx] = h;
}

// ============ K3b: window schedule ============
__global__ __launch_bounds__(512) void k_sched(const unsigned char* __restrict__ dones,
                                               int* __restrict__ tlo,
                                               unsigned char* __restrict__ usehid){
  int k = blockIdx.x;         // 0..7
  int b = threadIdx.x;        // 0..511
  int t0 = 0, uh = 1;
  if (k > 0){
    for (int t = 32*k; t >= 0; t--){
      if (dones[(size_t)t*B_DIM + b]){ t0 = t; uh = 0; break; }
    }
  }
  usehid[k*B_DIM + b] = (unsigned char)uh;
  __shared__ int red[512];
  red[b] = t0; __syncthreads();
  if (b < 32){
    int m = red[b*16];
    #pragma unroll
    for (int i=1;i<16;i++) m = min(m, red[b*16+i]);
    tlo[k*32 + b] = m;
  }
}

// ============ K4: fused normalize -> emb(MFMA) -> relu -> xg(MFMA) ============
// xg r/z outputs are (acc + bh_g) * log2e; n outputs are acc * 2log2e — the GRU
// consumes them as ready-made exp2 arguments.
__global__ __launch_bounds__(512) void k_embxg(const float* __restrict__ obs,
                                               const float* __restrict__ wsM,
                                               const float* __restrict__ wsI,
                                               const short* __restrict__ Bemb,
                                               const float* __restrict__ b_emb,
                                               const short* __restrict__ BWi,
                                               const float* __restrict__ bh,
                                               short* __restrict__ xgpk){
  int tid=threadIdx.x, w=tid>>6, lane=tid&63, q=lane>>4, l=lane&15;
  int rt = blockIdx.x;
  int r0 = rt*16;
  __shared__ __align__(16) short obsL[16*136];
  __shared__ __align__(16) short embL[16*136];

  {
    int row = tid>>5, seg = tid&31;
    f32x4 o = *(const f32x4*)(obs + (size_t)(r0+row)*D_DIM + seg*4);
    f32x4 m = *(const f32x4*)(wsM + seg*4);
    f32x4 iv= *(const f32x4*)(wsI + seg*4);
    bf16x4 v;
    v[0]=f2bf((o[0]-m[0])*iv[0]); v[1]=f2bf((o[1]-m[1])*iv[1]);
    v[2]=f2bf((o[2]-m[2])*iv[2]); v[3]=f2bf((o[3]-m[3])*iv[3]);
    *(bf16x4*)&obsL[swz(row, seg*4)] = v;
  }
  __syncthreads();

  bf16x8 A[4];
  #pragma unroll
  for (int kb=0;kb<4;kb++) A[kb] = *(const bf16x8*)&obsL[swz(l, kb*32+q*8)];

  const bf16x8* BE = (const bf16x8*)Bemb;
  f32x4 accE = {0.f,0.f,0.f,0.f};
  #pragma unroll
  for (int kb=0;kb<4;kb++)
    accE = __builtin_amdgcn_mfma_f32_16x16x32_bf16(A[kb], BE[(w*4+kb)*64+lane], accE, 0,0,0);
  {
    float bb = b_emb[w*16 + l];
    #pragma unroll
    for (int r2=0;r2<4;r2++){
      float e = accE[r2] + bb; e = e>0.f ? e : 0.f;
      int b = q*4+r2;
      embL[swz(b, w*16+l)] = f2bf(e);
    }
  }
  __syncthreads();

  bf16x8 A2[4];
  #pragma unroll
  for (int kb=0;kb<4;kb++) A2[kb] = *(const bf16x8*)&embL[swz(l, kb*32+q*8)];

  const bf16x8* BW = (const bf16x8*)BWi;
  bf16x4* xg4 = (bf16x4*)xgpk;
  #pragma unroll
  for (int g=0; g<3; g++){
    int ct = g*8 + w;
    f32x4 acc = {0.f,0.f,0.f,0.f};
    #pragma unroll
    for (int kb=0;kb<4;kb++)
      acc = __builtin_amdgcn_mfma_f32_16x16x32_bf16(A2[kb], BW[(ct*4+kb)*64+lane], acc, 0,0,0);
    int col = ct*16 + l;
    float bb = (g<2) ? bh[col] : 0.f;
    float sc = (g<2) ? LOG2E : (2.f*LOG2E);
    bf16x4 v;
    v[0]=f2bf((acc[0]+bb)*sc); v[1]=f2bf((acc[1]+bb)*sc);
    v[2]=f2bf((acc[2]+bb)*sc); v[3]=f2bf((acc[3]+bb)*sc);
    xg4[((size_t)rt*24 + ct)*64 + lane] = v;
  }
}

// ============ K5: window-parallel GRU ============
// v2 changes (this round):
//  - raw s_barrier + lgkmcnt(0)-only sync: removes the vmcnt(0) drain that
//    __syncthreads lowers to, so the xg/dones prefetch loads and ys stores
//    stay in flight across the barrier (counted-vmcnt discipline).
//    Safety: lgkmcnt(0) covers this wave's ds reads+writes before it arrives;
//    double-buffered hF puts a full barrier between read(buf)@t and
//    write(buf)@t+2.
//  - exp2/rcp builtins; log2e and bh_r/bh_z pre-folded into BWh/xg, so each
//    sigmoid is {add, v_exp(-x), add, v_rcp} — no v_div expansion, no mul.
//  - XOR-swizzled hF: kills the ~8-way bank conflict on the ds_read_b128
//    A-fragment reads (was 4.7M conflict cycles/dispatch).
#define LDB(g,kb) __builtin_bit_cast(f16x8, pw4[(((g)*8+w)*4+(kb))*64+lane])
__global__
__attribute__((amdgpu_flat_work_group_size(512,512)))
__attribute__((amdgpu_waves_per_eu(2,2)))
void k_gru(const float* __restrict__ hidden,
           const unsigned char* __restrict__ dones,
           const short* __restrict__ xgpk,
           const short* __restrict__ BWh,
           const float* __restrict__ bh,
           const int* __restrict__ tlo,
           const unsigned char* __restrict__ usehid,
           short* __restrict__ yspk,
           float* __restrict__ h_last){
  int tid=threadIdx.x, w=tid>>6, lane=tid&63, q=lane>>4, l=lane&15;
  int kk = blockIdx.x >> 5, bt = blockIdx.x & 31;
  int t_out0 = kk*32;
  int t_end  = t_out0 + 32;
  int t_start = tlo[kk*32 + bt];

  __shared__ __align__(16) _Float16 hF[2][16*136];   // 8704 B, swizzled

  // 12 B-fragments, loaded once, individually named SSA values.
  const u32x4* pw4 = (const u32x4*)BWh;
  f16x8 B00 = LDB(0,0), B01 = LDB(0,1), B02 = LDB(0,2), B03 = LDB(0,3);
  f16x8 B10 = LDB(1,0), B11 = LDB(1,1), B12 = LDB(1,2), B13 = LDB(1,3);
  f16x8 B20 = LDB(2,0), B21 = LDB(2,1), B22 = LDB(2,2), B23 = LDB(2,3);

  // only the n-gate bias survives in-kernel (it sits inside r*(...)),
  // pre-scaled by 2*log2e to match the pre-scaled Wh_n / xg_n.
  float bh2c = bh[2*128 + w*16 + l] * (2.f*LOG2E);

  float hv[4];
  #pragma unroll
  for (int r2=0;r2<4;r2++){
    int b = bt*16 + q*4 + r2;
    hv[r2] = usehid[kk*B_DIM + b] ? hidden[(size_t)b*H_DIM + w*16 + l] : 0.f;
  }

  // running pointers (uniform per-iter strides)
  const bf16x4* xgt = (const bf16x4*)xgpk + (((size_t)t_start*32 + bt)*24 + w)*64 + lane;
  const unsigned char* dnp = dones + (size_t)t_start*B_DIM + bt*16 + q*4;
  bf16x4* yst = (bf16x4*)yspk + (((size_t)t_start*32 + bt)*8 + w)*64 + lane;

  bf16x4 xr_c = xgt[0], xz_c = xgt[512], xn_c = xgt[1024];   // gate stride 8*64
  unsigned dn_c = *(const unsigned*)dnp;

  for (int t = t_start; t < t_end; t++){
    int buf = t & 1;
    #pragma unroll
    for (int r2=0;r2<4;r2++){
      float hvv = ((dn_c >> (r2*8)) & 255u) ? 0.f : hv[r2];
      hv[r2] = hvv;
      int b = q*4+r2;
      hF[buf][swz(b, w*16+l)] = (_Float16)hvv;
    }
    // lgkm-only barrier: own LDS traffic drained, VMEM stays in flight.
    asm volatile("s_waitcnt lgkmcnt(0)" ::: "memory");
    __builtin_amdgcn_s_barrier();
    asm volatile("" ::: "memory");

    // advance + prefetch step t+1 (advance 0 on last iter -> no OOB)
    int adv = (t+1 < t_end) ? 1 : 0;
    xgt += (size_t)adv * 49152;       // 32 tiles * 24 * 64
    dnp += adv * B_DIM;
    bf16x4 xr_n = xgt[0], xz_n = xgt[512], xn_n = xgt[1024];
    unsigned dn_n = *(const unsigned*)dnp;

    const _Float16* hb = &hF[buf][0];
    f16x8 A0 = *(const f16x8*)(hb + swz(l,  0 + q*8));
    f16x8 A1 = *(const f16x8*)(hb + swz(l, 32 + q*8));
    f16x8 A2 = *(const f16x8*)(hb + swz(l, 64 + q*8));
    f16x8 A3 = *(const f16x8*)(hb + swz(l, 96 + q*8));

    f32x4 acc0 = {0.f,0.f,0.f,0.f}, acc1 = {0.f,0.f,0.f,0.f}, acc2 = {0.f,0.f,0.f,0.f};
    acc0 = __builtin_amdgcn_mfma_f32_16x16x32_f16(A0, B00, acc0, 0,0,0);
    acc1 = __builtin_amdgcn_mfma_f32_16x16x32_f16(A0, B10, acc1, 0,0,0);
    acc2 = __builtin_amdgcn_mfma_f32_16x16x32_f16(A0, B20, acc2, 0,0,0);
    acc0 = __builtin_amdgcn_mfma_f32_16x16x32_f16(A1, B01, acc0, 0,0,0);
    acc1 = __builtin_amdgcn_mfma_f32_16x16x32_f16(A1, B11, acc1, 0,0,0);
    acc2 = __builtin_amdgcn_mfma_f32_16x16x32_f16(A1, B21, acc2, 0,0,0);
    acc0 = __builtin_amdgcn_mfma_f32_16x16x32_f16(A2, B02, acc0, 0,0,0);
    acc1 = __builtin_amdgcn_mfma_f32_16x16x32_f16(A2, B12, acc1, 0,0,0);
    acc2 = __builtin_amdgcn_mfma_f32_16x16x32_f16(A2, B22, acc2, 0,0,0);
    acc0 = __builtin_amdgcn_mfma_f32_16x16x32_f16(A3, B03, acc0, 0,0,0);
    acc1 = __builtin_amdgcn_mfma_f32_16x16x32_f16(A3, B13, acc1, 0,0,0);
    acc2 = __builtin_amdgcn_mfma_f32_16x16x32_f16(A3, B23, acc2, 0,0,0);

    #pragma unroll
    for (int r2=0;r2<4;r2++){
      // xr/xz already = (xg+bh)*log2e; xn already = xg*2log2e; Wh pre-scaled.
      float xr = bf2f(xr_c[r2]), xz = bf2f(xz_c[r2]), xn = bf2f(xn_c[r2]);
      float rg = __builtin_amdgcn_rcpf(1.f + __builtin_amdgcn_exp2f(-(xr + acc0[r2])));
      float zg = __builtin_amdgcn_rcpf(1.f + __builtin_amdgcn_exp2f(-(xz + acc1[r2])));
      float e2 = __builtin_amdgcn_exp2f(xn + rg*(acc2[r2] + bh2c));   // 2^(2nu*log2e)
      float ng = 1.f - 2.f*__builtin_amdgcn_rcpf(e2 + 1.f);           // tanh, inf-safe
      hv[r2] = ng + zg*(hv[r2] - ng);
    }
    if (t >= t_out0){
      bf16x4 yv;
      yv[0]=f2bf(hv[0]); yv[1]=f2bf(hv[1]); yv[2]=f2bf(hv[2]); yv[3]=f2bf(hv[3]);
      *yst = yv;
    }
    yst += 16384;                     // 32 tiles * 8 * 64 (advance always; deref gated)
    xr_c = xr_n; xz_c = xz_n; xn_c = xn_n; dn_c = dn_n;
  }

  if (kk == NWIN-1){
    #pragma unroll
    for (int r2=0;r2<4;r2++)
      h_last[(size_t)(bt*16+q*4+r2)*H_DIM + w*16 + l] = hv[r2];
  }
}

// ============ K6: act = relu(ys@W_act+b); alpha/beta = softplus(act@W+b)+1 ============
__global__ __launch_bounds__(256) void k_heads(const short* __restrict__ yspk,
                                               const short* __restrict__ Bact,
                                               const float* __restrict__ b_act,
                                               const short* __restrict__ Bhead,
                                               const float* __restrict__ b_alpha,
                                               const float* __restrict__ b_beta,
                                               float* __restrict__ alpha,
                                               float* __restrict__ beta){
  int tid=threadIdx.x, w=tid>>6, lane=tid&63, q=lane>>4, l=lane&15;
  size_t rt = (size_t)blockIdx.x*4 + w;
  __shared__ __align__(16) short tl[4][16*136];
  const bf16x4* ys4 = (const bf16x4*)yspk;
  #pragma unroll
  for (int ct=0; ct<8; ct++){
    bf16x4 v = ys4[(rt*8+ct)*64+lane];
    #pragma unroll
    for (int r2=0;r2<4;r2++){ int b=q*4+r2; tl[w][swz(b, ct*16+l)] = v[r2]; }
  }
  __syncthreads();
  bf16x8 A[4];
  #pragma unroll
  for (int kb=0;kb<4;kb++) A[kb] = *(const bf16x8*)&tl[w][swz(l, kb*32+q*8)];
  __syncthreads();
  const bf16x8* BA = (const bf16x8*)Bact;
  f32x4 accA[8];
  #pragma unroll
  for (int ct=0;ct<8;ct++){ f32x4 z = {0.f,0.f,0.f,0.f}; accA[ct]=z; }
  #pragma unroll
  for (int ct=0;ct<8;ct++)
    #pragma unroll
    for (int kb=0;kb<4;kb++)
      accA[ct] = __builtin_amdgcn_mfma_f32_16x16x32_bf16(A[kb], BA[(ct*4+kb)*64+lane], accA[ct], 0,0,0);
  #pragma unroll
  for (int ct=0;ct<8;ct++){
    int col = ct*16 + l;
    float bb = b_act[col];
    #pragma unroll
    for (int r2=0;r2<4;r2++){
      float e = accA[ct][r2] + bb; e = e>0.f ? e : 0.f;
      int b = q*4+r2;
      tl[w][swz(b, col)] = f2bf(e);
    }
  }
  __syncthreads();
  bf16x8 A2[4];
  #pragma unroll
  for (int kb=0;kb<4;kb++) A2[kb] = *(const bf16x8*)&tl[w][swz(l, kb*32+q*8)];
  const bf16x8* BHd = (const bf16x8*)Bhead;
  f32x4 acc = {0.f,0.f,0.f,0.f};
  #pragma unroll
  for (int kb=0;kb<4;kb++)
    acc = __builtin_amdgcn_mfma_f32_16x16x32_bf16(A2[kb], BHd[kb*64+lane], acc, 0,0,0);
  float bb = (l<8) ? b_alpha[l] : b_beta[l-8];
  float* dst = (l<8) ? alpha : beta;
  int cc = (l<8) ? l : l-8;
  #pragma unroll
  for (int r2=0;r2<4;r2++){
    float u = acc[r2] + bb;
    // softplus via v_exp/v_log: max(u,0) + ln(1+2^(-|u|*log2e))
    float e = __builtin_amdgcn_exp2f(-fabsf(u)*LOG2E);
    float sp = fmaxf(u,0.f) + 0.6931471805599453f*__builtin_amdgcn_logf(1.f + e);
    dst[(rt*16 + q*4 + r2)*8 + cc] = sp + 1.f;
  }
}

// ================= host launcher =================
extern "C" void kernel_launch(void* const* d_in, const int* in_sizes, int n_in,
                              void* d_out, int out_size, void* d_ws, size_t ws_size,
                              hipStream_t stream){
  const float* hidden   = (const float*)d_in[0];
  const float* obs      = (const float*)d_in[1];
  const unsigned char* dones = (const unsigned char*)d_in[2];
  const float* mean_obs = (const float*)d_in[3];
  const float* welfS    = (const float*)d_in[4];
  const int*   runcnt   = (const int*)d_in[5];
  const float* W_emb = (const float*)d_in[6];
  const float* b_emb = (const float*)d_in[7];
  const float* Wi    = (const float*)d_in[8];
  const float* Wh    = (const float*)d_in[9];
  const float* bh    = (const float*)d_in[10];
  const float* W_act = (const float*)d_in[11];
  const float* b_act = (const float*)d_in[12];
  const float* W_al  = (const float*)d_in[13];
  const float* b_al  = (const float*)d_in[14];
  const float* W_be  = (const float*)d_in[15];
  const float* b_be  = (const float*)d_in[16];
  float* out = (float*)d_out;
  char*  ws  = (char*)d_ws;

  double* psum = (double*)(ws + OFF_PSUM);
  double* psq  = (double*)(ws + OFF_PSQ);
  float*  wsM  = (float*)(ws + OFF_STATM);
  float*  wsI  = (float*)(ws + OFF_STATI);
  short*  Bemb = (short*)(ws + OFF_WEMB);
  short*  BWi  = (short*)(ws + OFF_WI);
  short*  BWh  = (short*)(ws + OFF_WH);
  short*  Bact = (short*)(ws + OFF_WACT);
  short*  Bhead= (short*)(ws + OFF_WHEAD);
  int*    tlo  = (int*)(ws + OFF_TLO);
  unsigned char* uh = (unsigned char*)(ws + OFF_UH);
  short*  xgpk = (short*)(ws + OFF_XG);
  short*  yspk = (short*)(ws + OFF_YS);

  k_partial<<<1024,256,0,stream>>>(obs, psum, psq);
  k_stats<<<1,1024,0,stream>>>(psum, psq, mean_obs, welfS, runcnt,
                               out+OUT_M, out+OUT_S, wsM, wsI);
  k_sched<<<8,512,0,stream>>>(dones, tlo, uh);
  k_pack_all<<<520,256,0,stream>>>(W_emb, Wi, Wh, W_act, W_al, W_be,
                                   Bemb, BWi, BWh, Bact, Bhead);
  k_embxg<<<8192,512,0,stream>>>(obs, wsM, wsI, Bemb, b_emb, BWi, bh, xgpk);
  k_gru<<<256,512,0,stream>>>(hidden, dones, xgpk, BWh, bh, tlo, uh,
                              yspk, out + OUT_H);
  k_heads<<<2048,256,0,stream>>>(yspk, Bact, b_act, Bhead, b_al, b_be,
                                 out + OUT_ALPHA, out + OUT_BETA);
}

// Round 2
// 498.973 us; speedup vs baseline: 1.2494x; 1.0212x over previous
//
#include <hip/hip_runtime.h>

// ---------------- problem dims ----------------
#define T_DIM 256
#define B_DIM 512
#define D_DIM 128
#define H_DIM 128
#define A_DIM 8
#define N_ROWS (T_DIM*B_DIM)   // 131072 flattened rows
#define NT (N_ROWS/16)         // 8192 row tiles of 16
#define NWIN 8                 // time windows of 32 for the GRU
#define LOG2E 1.4426950408889634f

typedef __attribute__((ext_vector_type(4))) float f32x4;
typedef __attribute__((ext_vector_type(8))) short bf16x8;     // 8 bf16 in 4 VGPRs
typedef __attribute__((ext_vector_type(4))) short bf16x4;
typedef __attribute__((ext_vector_type(8))) _Float16 f16x8;   // 8 f16 in 4 VGPRs
typedef __attribute__((ext_vector_type(4))) unsigned u32x4;
typedef __attribute__((ext_vector_type(2))) unsigned u32x2;

// ---------------- workspace layout (bytes) ----------------
#define OFF_PSUM   0ull
#define OFF_PSQ    1048576ull
#define OFF_STATM  2097152ull
#define OFF_STATI  2097664ull
#define OFF_WEMB   2098176ull              // 16384 el bf16
#define OFF_WI     2130944ull              // 49152 el bf16
#define OFF_WH     2229248ull              // 49152 el f16 (pre-scaled by log2e / 2log2e)
#define OFF_WACT   2425856ull              // 16384 el bf16
#define OFF_WHEAD  2458624ull              // 2048 el bf16
#define OFF_TLO    2462720ull              // 8*32 int
#define OFF_UH     2463744ull              // 8*512 bytes
#define OFF_XG     4194304ull              // 96 MB (C/D-frag order; r/z pre-biased+scaled)
#define OFF_YS     104857600ull            // 32 MB (C/D-frag order)

// ---------------- output layout (f32 elements) ----------------
#define OUT_H      0
#define OUT_ALPHA  65536
#define OUT_BETA   1114112
#define OUT_M      2162688
#define OUT_S      2162816

__device__ inline short f2bf(float x){              // RNE f32->bf16
  union { float f; unsigned u; } v; v.f = x;
  unsigned r = v.u + 0x7FFFu + ((v.u>>16)&1u);
  return (short)(r>>16);
}
__device__ inline float bf2f(short h){
  union { unsigned u; float f; } v; v.u = ((unsigned)(unsigned short)h)<<16; return v.f;
}

// LDS tile index. REVERTED to plain 136-stride (R1 post-mortem): for the
// b128 A-fragment reads this layout's bank-group = (l+q) mod 8, already
// perfectly balanced (8 lanes per 4-bank group = structural b128 minimum);
// the R1 XOR swizzle piled 16 lanes on one group (conflicts 4.7M -> 18.9M).
__device__ inline int swz(int row, int col){ return row*136 + col; }

// 2x f32 -> packed bf16 (RNE), matches f2bf rounding. 16 VALU -> 2 inst.
__device__ inline unsigned cvtpk_bf16(float lo, float hi){
  unsigned r;
  asm("v_cvt_pk_bf16_f32 %0, %1, %2" : "=v"(r) : "v"(lo), "v"(hi));
  return r;
}

// ============ K1: per-column partial sum / sumsq over obs rows ============
__global__ __launch_bounds__(256) void k_partial(const float* __restrict__ obs,
                                                 double* __restrict__ psum,
                                                 double* __restrict__ psq){
  int tid = threadIdx.x; int col = tid & 127; int rh = tid >> 7;
  double s = 0.0, q = 0.0;
  for (int r = blockIdx.x*2 + rh; r < N_ROWS; r += 2048){
    float v = obs[(size_t)r*D_DIM + col];
    s += (double)v; q += (double)v*(double)v;
  }
  __shared__ double ls[256], lq[256];
  ls[tid]=s; lq[tid]=q; __syncthreads();
  if (rh==0){
    psum[(size_t)blockIdx.x*128 + col] = ls[tid] + ls[tid+128];
    psq [(size_t)blockIdx.x*128 + col] = lq[tid] + lq[tid+128];
  }
}

// ============ K2: finalize Welford (chunk-combine) ============
__global__ __launch_bounds__(1024) void k_stats(const double* __restrict__ psum,
                                                const double* __restrict__ psq,
                                                const float* __restrict__ mean_obs,
                                                const float* __restrict__ welfS,
                                                const int* __restrict__ runcnt,
                                                float* __restrict__ outM, float* __restrict__ outS,
                                                float* __restrict__ wsM,  float* __restrict__ wsI){
  int tid = threadIdx.x; int col = tid & 127; int seg = tid >> 7;
  double s=0.0, q=0.0;
  for (int b=seg; b<1024; b+=8){ s += psum[(size_t)b*128+col]; q += psq[(size_t)b*128+col]; }
  __shared__ double ls[1024], lq[1024];
  ls[tid]=s; lq[tid]=q; __syncthreads();
  if (seg==0){
    for (int b=1;b<8;b++){ s += ls[b*128+col]; q += lq[b*128+col]; }
    double c0 = (double)runcnt[0];
    double Nn = (double)N_ROWS;
    double n  = c0 + Nn;
    double M0 = (double)mean_obs[col], S0 = (double)welfS[col];
    double mb = s / Nn;
    double delta = mb - M0;
    double M = M0 + delta * Nn / n;
    double M2b = q - Nn*mb*mb;
    double S = S0 + M2b + delta*delta*c0*Nn/n;
    double var = S / (n - 1.0);
    float inv = (float)(1.0/(sqrt(var)+1e-8));
    outM[col] = (float)M; outS[col] = (float)S;
    wsM[col]  = (float)M; wsI[col]  = inv;
  }
}

// ============ K3: all weight packs in ONE launch ============
// frag layout: ((ct*4+kb)*64+lane)*8+j holds W[k=kb*32+(lane>>4)*8+j][n=ct*16+(lane&15)]
// Wh (fmt=1) is pre-scaled: r/z columns x log2e, n columns x 2*log2e, so the
// GRU gate transcendentals become a single v_exp_f32 (exp2) each.
__global__ void k_pack_all(const float* __restrict__ W_emb, const float* __restrict__ Wi,
                           const float* __restrict__ Wh,    const float* __restrict__ W_act,
                           const float* __restrict__ W_al,  const float* __restrict__ W_be,
                           short* __restrict__ Bemb, short* __restrict__ BWi,
                           short* __restrict__ BWh,  short* __restrict__ Bact,
                           short* __restrict__ Bhead){
  int gidx = blockIdx.x*256 + threadIdx.x;
  if (gidx >= 133120) return;
  if (gidx >= 131072){
    int idx = gidx - 131072;
    int j = idx & 7, lane = (idx>>3)&63, kb = (idx>>9)&3;
    int k = kb*32 + (lane>>4)*8 + j;
    int n = lane & 15;
    float wv = (n<8) ? W_al[(size_t)k*8 + n] : W_be[(size_t)k*8 + (n-8)];
    Bhead[idx] = f2bf(wv);
    return;
  }
  const float* src; short* dst; int C; int fmt; int idx;   // fmt 0=bf16 1=f16
  if (gidx < 16384)      { src=W_emb; dst=Bemb; C=128; fmt=0; idx=gidx; }
  else if (gidx < 65536) { src=Wi;    dst=BWi;  C=384; fmt=0; idx=gidx-16384; }
  else if (gidx < 114688){ src=Wh;    dst=BWh;  C=384; fmt=1; idx=gidx-65536; }
  else                   { src=W_act; dst=Bact; C=128; fmt=0; idx=gidx-114688; }
  int j = idx & 7, lane = (idx>>3)&63, kb = (idx>>9)&3, ct = idx>>11;
  int k = kb*32 + (lane>>4)*8 + j;
  int n = ct*16 + (lane&15);
  float wv = src[(size_t)k*C + n];
  short h;
  if (fmt==0) h = f2bf(wv);
  else {
    wv *= (n < 256) ? LOG2E : (2.f*LOG2E);
    union { _Float16 hf; short s; } u; u.hf = (_Float16)wv; h = u.s;
  }
  dst[idx] = h;
}

// ============ K3b: window schedule ============
__global__ __launch_bounds__(512) void k_sched(const unsigned char* __restrict__ dones,
                                               int* __restrict__ tlo,
                                               unsigned char* __restrict__ usehid){
  int k = blockIdx.x;         // 0..7
  int b = threadIdx.x;        // 0..511
  int t0 = 0, uh = 1;
  if (k > 0){
    for (int t = 32*k; t >= 0; t--){
      if (dones[(size_t)t*B_DIM + b]){ t0 = t; uh = 0; break; }
    }
  }
  usehid[k*B_DIM + b] = (unsigned char)uh;
  __shared__ int red[512];
  red[b] = t0; __syncthreads();
  if (b < 32){
    int m = red[b*16];
    #pragma unroll
    for (int i=1;i<16;i++) m = min(m, red[b*16+i]);
    tlo[k*32 + b] = m;
  }
}

// ============ K4: fused normalize -> emb(MFMA) -> relu -> xg(MFMA) ============
// xg r/z outputs are (acc + bh_g) * log2e; n outputs are acc * 2log2e — the GRU
// consumes them as ready-made exp2 arguments.
__global__ __launch_bounds__(512) void k_embxg(const float* __restrict__ obs,
                                               const float* __restrict__ wsM,
                                               const float* __restrict__ wsI,
                                               const short* __restrict__ Bemb,
                                               const float* __restrict__ b_emb,
                                               const short* __restrict__ BWi,
                                               const float* __restrict__ bh,
                                               short* __restrict__ xgpk){
  int tid=threadIdx.x, w=tid>>6, lane=tid&63, q=lane>>4, l=lane&15;
  int rt = blockIdx.x;
  int r0 = rt*16;
  __shared__ __align__(16) short obsL[16*136];
  __shared__ __align__(16) short embL[16*136];

  {
    int row = tid>>5, seg = tid&31;
    f32x4 o = *(const f32x4*)(obs + (size_t)(r0+row)*D_DIM + seg*4);
    f32x4 m = *(const f32x4*)(wsM + seg*4);
    f32x4 iv= *(const f32x4*)(wsI + seg*4);
    bf16x4 v;
    v[0]=f2bf((o[0]-m[0])*iv[0]); v[1]=f2bf((o[1]-m[1])*iv[1]);
    v[2]=f2bf((o[2]-m[2])*iv[2]); v[3]=f2bf((o[3]-m[3])*iv[3]);
    *(bf16x4*)&obsL[swz(row, seg*4)] = v;
  }
  __syncthreads();

  bf16x8 A[4];
  #pragma unroll
  for (int kb=0;kb<4;kb++) A[kb] = *(const bf16x8*)&obsL[swz(l, kb*32+q*8)];

  const bf16x8* BE = (const bf16x8*)Bemb;
  f32x4 accE = {0.f,0.f,0.f,0.f};
  #pragma unroll
  for (int kb=0;kb<4;kb++)
    accE = __builtin_amdgcn_mfma_f32_16x16x32_bf16(A[kb], BE[(w*4+kb)*64+lane], accE, 0,0,0);
  {
    float bb = b_emb[w*16 + l];
    #pragma unroll
    for (int r2=0;r2<4;r2++){
      float e = accE[r2] + bb; e = e>0.f ? e : 0.f;
      int b = q*4+r2;
      embL[swz(b, w*16+l)] = f2bf(e);
    }
  }
  __syncthreads();

  bf16x8 A2[4];
  #pragma unroll
  for (int kb=0;kb<4;kb++) A2[kb] = *(const bf16x8*)&embL[swz(l, kb*32+q*8)];

  const bf16x8* BW = (const bf16x8*)BWi;
  u32x2* xg8 = (u32x2*)xgpk;
  #pragma unroll
  for (int g=0; g<3; g++){
    int ct = g*8 + w;
    f32x4 acc = {0.f,0.f,0.f,0.f};
    #pragma unroll
    for (int kb=0;kb<4;kb++)
      acc = __builtin_amdgcn_mfma_f32_16x16x32_bf16(A2[kb], BW[(ct*4+kb)*64+lane], acc, 0,0,0);
    int col = ct*16 + l;
    float bb = (g<2) ? bh[col] : 0.f;
    float sc = (g<2) ? LOG2E : (2.f*LOG2E);
    u32x2 pv;
    pv[0] = cvtpk_bf16((acc[0]+bb)*sc, (acc[1]+bb)*sc);
    pv[1] = cvtpk_bf16((acc[2]+bb)*sc, (acc[3]+bb)*sc);
    xg8[((size_t)rt*24 + ct)*64 + lane] = pv;
  }
}

// ============ K5: window-parallel GRU ============
// v3 changes (this round):
//  - REVERT the R1 XOR swizzle on hF (it quadrupled bank conflicts; plain
//    136-stride reads are already 8-lanes/4-bank-group balanced).
//  - 2-deep xg/dones prefetch with named register rotation (rule #20):
//    xg is a 96MB stream (>> L2), so gate loads are ~900cy HBM misses;
//    depth-1 rotation lets register reuse serialize load->use at one HBM
//    latency per step. Depth-2 puts ~2 steps between issue and use.
//  - ys store packing via v_cvt_pk_bf16_f32 (16 VALU -> 2 inst, same RNE).
#define LDB(g,kb) __builtin_bit_cast(f16x8, pw4[(((g)*8+w)*4+(kb))*64+lane])
__global__
__attribute__((amdgpu_flat_work_group_size(512,512)))
__attribute__((amdgpu_waves_per_eu(2,2)))
void k_gru(const float* __restrict__ hidden,
           const unsigned char* __restrict__ dones,
           const short* __restrict__ xgpk,
           const short* __restrict__ BWh,
           const float* __restrict__ bh,
           const int* __restrict__ tlo,
           const unsigned char* __restrict__ usehid,
           short* __restrict__ yspk,
           float* __restrict__ h_last){
  int tid=threadIdx.x, w=tid>>6, lane=tid&63, q=lane>>4, l=lane&15;
  int kk = blockIdx.x >> 5, bt = blockIdx.x & 31;
  int t_out0 = kk*32;
  int t_end  = t_out0 + 32;
  int t_start = tlo[kk*32 + bt];

  __shared__ __align__(16) _Float16 hF[2][16*136];   // 8704 B

  // 12 B-fragments, loaded once, individually named SSA values.
  const u32x4* pw4 = (const u32x4*)BWh;
  f16x8 B00 = LDB(0,0), B01 = LDB(0,1), B02 = LDB(0,2), B03 = LDB(0,3);
  f16x8 B10 = LDB(1,0), B11 = LDB(1,1), B12 = LDB(1,2), B13 = LDB(1,3);
  f16x8 B20 = LDB(2,0), B21 = LDB(2,1), B22 = LDB(2,2), B23 = LDB(2,3);

  // only the n-gate bias survives in-kernel (it sits inside r*(...)),
  // pre-scaled by 2*log2e to match the pre-scaled Wh_n / xg_n.
  float bh2c = bh[2*128 + w*16 + l] * (2.f*LOG2E);

  float hv[4];
  #pragma unroll
  for (int r2=0;r2<4;r2++){
    int b = bt*16 + q*4 + r2;
    hv[r2] = usehid[kk*B_DIM + b] ? hidden[(size_t)b*H_DIM + w*16 + l] : 0.f;
  }

  // running pointers (uniform per-iter strides)
  const bf16x4* xgt = (const bf16x4*)xgpk + (((size_t)t_start*32 + bt)*24 + w)*64 + lane;
  const unsigned char* dnp = dones + (size_t)t_start*B_DIM + bt*16 + q*4;
  bf16x4* yst = (bf16x4*)yspk + (((size_t)t_start*32 + bt)*8 + w)*64 + lane;

  // 2-deep prefetch pipeline: _c = step t, _n = step t+1.
  bf16x4 xr_c = xgt[0], xz_c = xgt[512], xn_c = xgt[1024];   // gate stride 8*64
  unsigned dn_c = *(const unsigned*)dnp;
  { int a1 = (t_start+1 < t_end) ? 1 : 0; xgt += (size_t)a1*49152; dnp += a1*B_DIM; }
  bf16x4 xr_n = xgt[0], xz_n = xgt[512], xn_n = xgt[1024];
  unsigned dn_n = *(const unsigned*)dnp;

  // double-buffer base pointers, swapped per iteration (loop-invariant
  // write/read offsets become immediate ds offsets).
  _Float16* hA = &hF[0][0];
  _Float16* hB = &hF[1][0];
  const int wo = q*4*136 + w*16 + l;     // write offset, +r2*136 per row
  const int ro = l*136 + q*8;            // read offset, +{0,32,64,96} per kb

  for (int t = t_start; t < t_end; t++){
    #pragma unroll
    for (int r2=0;r2<4;r2++){
      float hvv = ((dn_c >> (r2*8)) & 255u) ? 0.f : hv[r2];
      hv[r2] = hvv;
      hA[wo + r2*136] = (_Float16)hvv;
    }
    // lgkm-only barrier: own LDS traffic drained, VMEM stays in flight.
    asm volatile("s_waitcnt lgkmcnt(0)" ::: "memory");
    __builtin_amdgcn_s_barrier();
    asm volatile("" ::: "memory");

    // prefetch step t+2 (advance 0 near the end -> in-bounds reload)
    int a2 = (t+2 < t_end) ? 1 : 0;
    xgt += (size_t)a2 * 49152;       // 32 tiles * 24 * 64
    dnp += a2 * B_DIM;
    bf16x4 xr_2 = xgt[0], xz_2 = xgt[512], xn_2 = xgt[1024];
    unsigned dn_2 = *(const unsigned*)dnp;

    f16x8 A0 = *(const f16x8*)(hA + ro +  0);
    f16x8 A1 = *(const f16x8*)(hA + ro + 32);
    f16x8 A2 = *(const f16x8*)(hA + ro + 64);
    f16x8 A3 = *(const f16x8*)(hA + ro + 96);

    f32x4 acc0 = {0.f,0.f,0.f,0.f}, acc1 = {0.f,0.f,0.f,0.f}, acc2 = {0.f,0.f,0.f,0.f};
    acc0 = __builtin_amdgcn_mfma_f32_16x16x32_f16(A0, B00, acc0, 0,0,0);
    acc1 = __builtin_amdgcn_mfma_f32_16x16x32_f16(A0, B10, acc1, 0,0,0);
    acc2 = __builtin_amdgcn_mfma_f32_16x16x32_f16(A0, B20, acc2, 0,0,0);
    acc0 = __builtin_amdgcn_mfma_f32_16x16x32_f16(A1, B01, acc0, 0,0,0);
    acc1 = __builtin_amdgcn_mfma_f32_16x16x32_f16(A1, B11, acc1, 0,0,0);
    acc2 = __builtin_amdgcn_mfma_f32_16x16x32_f16(A1, B21, acc2, 0,0,0);
    acc0 = __builtin_amdgcn_mfma_f32_16x16x32_f16(A2, B02, acc0, 0,0,0);
    acc1 = __builtin_amdgcn_mfma_f32_16x16x32_f16(A2, B12, acc1, 0,0,0);
    acc2 = __builtin_amdgcn_mfma_f32_16x16x32_f16(A2, B22, acc2, 0,0,0);
    acc0 = __builtin_amdgcn_mfma_f32_16x16x32_f16(A3, B03, acc0, 0,0,0);
    acc1 = __builtin_amdgcn_mfma_f32_16x16x32_f16(A3, B13, acc1, 0,0,0);
    acc2 = __builtin_amdgcn_mfma_f32_16x16x32_f16(A3, B23, acc2, 0,0,0);

    #pragma unroll
    for (int r2=0;r2<4;r2++){
      // xr/xz already = (xg+bh)*log2e; xn already = xg*2log2e; Wh pre-scaled.
      float xr = bf2f(xr_c[r2]), xz = bf2f(xz_c[r2]), xn = bf2f(xn_c[r2]);
      float rg = __builtin_amdgcn_rcpf(1.f + __builtin_amdgcn_exp2f(-(xr + acc0[r2])));
      float zg = __builtin_amdgcn_rcpf(1.f + __builtin_amdgcn_exp2f(-(xz + acc1[r2])));
      float e2 = __builtin_amdgcn_exp2f(xn + rg*(acc2[r2] + bh2c));   // 2^(2nu*log2e)
      float ng = 1.f - 2.f*__builtin_amdgcn_rcpf(e2 + 1.f);           // tanh, inf-safe
      hv[r2] = ng + zg*(hv[r2] - ng);
    }
    if (t >= t_out0){
      u32x2 pv;
      pv[0] = cvtpk_bf16(hv[0], hv[1]);
      pv[1] = cvtpk_bf16(hv[2], hv[3]);
      *(u32x2*)yst = pv;
    }
    yst += 16384;                     // 32 tiles * 8 * 64 (advance always; deref gated)
    xr_c = xr_n; xz_c = xz_n; xn_c = xn_n; dn_c = dn_n;
    xr_n = xr_2; xz_n = xz_2; xn_n = xn_2; dn_n = dn_2;
    _Float16* tmp = hA; hA = hB; hB = tmp;
  }

  if (kk == NWIN-1){
    #pragma unroll
    for (int r2=0;r2<4;r2++)
      h_last[(size_t)(bt*16+q*4+r2)*H_DIM + w*16 + l] = hv[r2];
  }
}

// ============ K6: act = relu(ys@W_act+b); alpha/beta = softplus(act@W+b)+1 ============
__global__ __launch_bounds__(256) void k_heads(const short* __restrict__ yspk,
                                               const short* __restrict__ Bact,
                                               const float* __restrict__ b_act,
                                               const short* __restrict__ Bhead,
                                               const float* __restrict__ b_alpha,
                                               const float* __restrict__ b_beta,
                                               float* __restrict__ alpha,
                                               float* __restrict__ beta){
  int tid=threadIdx.x, w=tid>>6, lane=tid&63, q=lane>>4, l=lane&15;
  size_t rt = (size_t)blockIdx.x*4 + w;
  __shared__ __align__(16) short tl[4][16*136];
  const bf16x4* ys4 = (const bf16x4*)yspk;
  #pragma unroll
  for (int ct=0; ct<8; ct++){
    bf16x4 v = ys4[(rt*8+ct)*64+lane];
    #pragma unroll
    for (int r2=0;r2<4;r2++){ int b=q*4+r2; tl[w][swz(b, ct*16+l)] = v[r2]; }
  }
  __syncthreads();
  bf16x8 A[4];
  #pragma unroll
  for (int kb=0;kb<4;kb++) A[kb] = *(const bf16x8*)&tl[w][swz(l, kb*32+q*8)];
  __syncthreads();
  const bf16x8* BA = (const bf16x8*)Bact;
  f32x4 accA[8];
  #pragma unroll
  for (int ct=0;ct<8;ct++){ f32x4 z = {0.f,0.f,0.f,0.f}; accA[ct]=z; }
  #pragma unroll
  for (int ct=0;ct<8;ct++)
    #pragma unroll
    for (int kb=0;kb<4;kb++)
      accA[ct] = __builtin_amdgcn_mfma_f32_16x16x32_bf16(A[kb], BA[(ct*4+kb)*64+lane], accA[ct], 0,0,0);
  #pragma unroll
  for (int ct=0;ct<8;ct++){
    int col = ct*16 + l;
    float bb = b_act[col];
    #pragma unroll
    for (int r2=0;r2<4;r2++){
      float e = accA[ct][r2] + bb; e = e>0.f ? e : 0.f;
      int b = q*4+r2;
      tl[w][swz(b, col)] = f2bf(e);
    }
  }
  __syncthreads();
  bf16x8 A2[4];
  #pragma unroll
  for (int kb=0;kb<4;kb++) A2[kb] = *(const bf16x8*)&tl[w][swz(l, kb*32+q*8)];
  const bf16x8* BHd = (const bf16x8*)Bhead;
  f32x4 acc = {0.f,0.f,0.f,0.f};
  #pragma unroll
  for (int kb=0;kb<4;kb++)
    acc = __builtin_amdgcn_mfma_f32_16x16x32_bf16(A2[kb], BHd[kb*64+lane], acc, 0,0,0);
  float bb = (l<8) ? b_alpha[l] : b_beta[l-8];
  float* dst = (l<8) ? alpha : beta;
  int cc = (l<8) ? l : l-8;
  #pragma unroll
  for (int r2=0;r2<4;r2++){
    float u = acc[r2] + bb;
    // softplus via v_exp/v_log: max(u,0) + ln(1+2^(-|u|*log2e))
    float e = __builtin_amdgcn_exp2f(-fabsf(u)*LOG2E);
    float sp = fmaxf(u,0.f) + 0.6931471805599453f*__builtin_amdgcn_logf(1.f + e);
    dst[(rt*16 + q*4 + r2)*8 + cc] = sp + 1.f;
  }
}

// ================= host launcher =================
extern "C" void kernel_launch(void* const* d_in, const int* in_sizes, int n_in,
                              void* d_out, int out_size, void* d_ws, size_t ws_size,
                              hipStream_t stream){
  const float* hidden   = (const float*)d_in[0];
  const float* obs      = (const float*)d_in[1];
  const unsigned char* dones = (const unsigned char*)d_in[2];
  const float* mean_obs = (const float*)d_in[3];
  const float* welfS    = (const float*)d_in[4];
  const int*   runcnt   = (const int*)d_in[5];
  const float* W_emb = (const float*)d_in[6];
  const float* b_emb = (const float*)d_in[7];
  const float* Wi    = (const float*)d_in[8];
  const float* Wh    = (const float*)d_in[9];
  const float* bh    = (const float*)d_in[10];
  const float* W_act = (const float*)d_in[11];
  const float* b_act = (const float*)d_in[12];
  const float* W_al  = (const float*)d_in[13];
  const float* b_al  = (const float*)d_in[14];
  const float* W_be  = (const float*)d_in[15];
  const float* b_be  = (const float*)d_in[16];
  float* out = (float*)d_out;
  char*  ws  = (char*)d_ws;

  double* psum = (double*)(ws + OFF_PSUM);
  double* psq  = (double*)(ws + OFF_PSQ);
  float*  wsM  = (float*)(ws + OFF_STATM);
  float*  wsI  = (float*)(ws + OFF_STATI);
  short*  Bemb = (short*)(ws + OFF_WEMB);
  short*  BWi  = (short*)(ws + OFF_WI);
  short*  BWh  = (short*)(ws + OFF_WH);
  short*  Bact = (short*)(ws + OFF_WACT);
  short*  Bhead= (short*)(ws + OFF_WHEAD);
  int*    tlo  = (int*)(ws + OFF_TLO);
  unsigned char* uh = (unsigned char*)(ws + OFF_UH);
  short*  xgpk = (short*)(ws + OFF_XG);
  short*  yspk = (short*)(ws + OFF_YS);

  k_partial<<<1024,256,0,stream>>>(obs, psum, psq);
  k_stats<<<1,1024,0,stream>>>(psum, psq, mean_obs, welfS, runcnt,
                               out+OUT_M, out+OUT_S, wsM, wsI);
  k_sched<<<8,512,0,stream>>>(dones, tlo, uh);
  k_pack_all<<<520,256,0,stream>>>(W_emb, Wi, Wh, W_act, W_al, W_be,
                                   Bemb, BWi, BWh, Bact, Bhead);
  k_embxg<<<8192,512,0,stream>>>(obs, wsM, wsI, Bemb, b_emb, BWi, bh, xgpk);
  k_gru<<<256,512,0,stream>>>(hidden, dones, xgpk, BWh, bh, tlo, uh,
                              yspk, out + OUT_H);
  k_heads<<<2048,256,0,stream>>>(yspk, Bact, b_act, Bhead, b_al, b_be,
                                 out + OUT_ALPHA, out + OUT_BETA);
}